// Round 1
// 293.376 us; speedup vs baseline: 1.0341x; 1.0341x over previous
//
#include <hip/hip_runtime.h>
#include <stdint.h>

#define IMB 64              // images per block
#define NBLK (65536 / IMB)  // 1024 blocks
#define CHUNK_B 7168        // 64 rows * 112 B = 7 KB = 7 x 1KB wave-DMA ops
#define NCHUNK 28           // chunks per block (28 * 7168 = 64*784*4)

// ---- async global->LDS DMA (16B/lane, 1KB/wave-instruction, no VGPR cost) ----
__device__ __forceinline__ void gload16(const void* g, void* l) {
  __builtin_amdgcn_global_load_lds(
      (const __attribute__((address_space(1))) uint32_t*)g,
      (__attribute__((address_space(3))) uint32_t*)l, 16, 0, 0);
}

// counted vmcnt wait; memory clobber orders all memory ops, sched_barrier pins it
#define VMWAIT(N)                                                  \
  do {                                                             \
    asm volatile("s_waitcnt vmcnt(" #N ")" ::: "memory");          \
    __builtin_amdgcn_sched_barrier(0);                             \
  } while (0)

__device__ __forceinline__ void FA(uint32_t a, uint32_t b, uint32_t c,
                                   uint32_t& s, uint32_t& cy) {
  uint32_t ab = a ^ b;
  s = ab ^ c;
  cy = (a & b) | (ab & c);
}

// issue one 7KB chunk (7 x global_load_lds_dwordx4) into a wave-private slot
__device__ __forceinline__ void issue_chunk(const uint8_t* gsrc, uint8_t* slot,
                                            int c, int lane) {
  const uint8_t* s = gsrc + (size_t)c * CHUNK_B + lane * 16;
  uint8_t* d = slot + lane * 16;
#pragma unroll
  for (int i = 0; i < 7; ++i) gload16(s + i * 1024, d + i * 1024);
}

// one row per lane: 7 x ds_read_b128 -> 28 sign bits -> srows
__device__ __forceinline__ void proc_chunk(const uint8_t* slot, int c, int lane,
                                           uint32_t* srows) {
  const uint8_t* rp = slot + lane * 112;
  uint32_t m = 0;
#pragma unroll
  for (int q = 0; q < 7; ++q) {
    uint4 v = *(const uint4*)(rp + q * 16);
    uint32_t n = (v.x >> 31) | ((v.y >> 31) << 1) | ((v.z >> 31) << 2) |
                 ((v.w >> 31) << 3);
    m |= n << (4 * q);
  }
  uint32_t g = (uint32_t)c * 64u + (uint32_t)lane;  // block-local row id
  uint32_t img = g / 28u;
  uint32_t rowin = g - img * 28u;
  srows[img * 29 + rowin] = m;
}

// One fused kernel. Per block: 64 images.
//  stream: wave-private double-buffered global_load_lds DMA (14KB in flight/wave)
//  pack:   per-lane row assembly from LDS raw floats
//  conv+FC: 4 threads/image, CSA bit-plane binary conv + XNOR-popcount, shfl reduce
__global__ __launch_bounds__(256, 2) void bnn_fused(
    const float* __restrict__ x, const float* __restrict__ w_conv,
    const float* __restrict__ b_conv, const float* __restrict__ w_fc,
    const float* __restrict__ b_fc, float* __restrict__ out)
{
  __shared__ __align__(16) uint8_t  raw[4 * 2 * CHUNK_B];  // 57344 B staging
  __shared__ uint32_t srows[IMB * 29];                     // stride 29: conflict-free
  __shared__ __align__(16) uint32_t swf[900];              // packed w_fc [75 ci][12]
  const int tid = threadIdx.x;
  const int w = tid >> 6, lane = tid & 63;

  // conv weight sign masks (uniform addresses -> scalar loads / SGPRs)
  uint32_t wm[3][16], sbc[3];
#pragma unroll
  for (int c = 0; c < 3; ++c) {
#pragma unroll
    for (int uv = 0; uv < 16; ++uv)
      wm[c][uv] = (uint32_t)((int32_t)__float_as_uint(w_conv[c * 16 + uv]) >> 31);
    sbc[c] = (uint32_t)((int32_t)__float_as_uint(b_conv[c]) >> 31);
  }

  // unpack w_fc sign bits (redundant per block; 75 KB stays L2-resident)
  for (int s = tid; s < 750; s += 256) {
    int ci = s / 10, k = s - ci * 10;
    const float* wr = w_fc + k * 1875 + ci * 25;
    uint32_t m = 0;
#pragma unroll
    for (int j = 0; j < 25; ++j)
      m |= (__float_as_uint(wr[j]) >> 31) << j;
    swf[ci * 12 + k] = m;
  }

  // Drain ALL non-DMA vector loads so vmcnt counts below are exact.
  asm volatile("s_waitcnt vmcnt(0)" ::: "memory");
  __builtin_amdgcn_sched_barrier(0);

  // --- streaming phase: wave-private double-buffered DMA pipeline ---
  // wave w owns chunks {w, w+4, ..., w+24}; slot parity = chunk index & 1.
  // Only DMA ops touch vmcnt in this region (LDS ops are lgkmcnt).
  const uint8_t* gsrc = (const uint8_t*)(x + (size_t)blockIdx.x * (IMB * 784));
  uint8_t* slot0 = &raw[(w * 2 + 0) * CHUNK_B];
  uint8_t* slot1 = &raw[(w * 2 + 1) * CHUNK_B];

  issue_chunk(gsrc, slot0, w + 4 * 0, lane);
  issue_chunk(gsrc, slot1, w + 4 * 1, lane);
  VMWAIT(7); proc_chunk(slot0, w + 4 * 0, lane, srows);
  issue_chunk(gsrc, slot0, w + 4 * 2, lane);
  VMWAIT(7); proc_chunk(slot1, w + 4 * 1, lane, srows);
  issue_chunk(gsrc, slot1, w + 4 * 3, lane);
  VMWAIT(7); proc_chunk(slot0, w + 4 * 2, lane, srows);
  issue_chunk(gsrc, slot0, w + 4 * 4, lane);
  VMWAIT(7); proc_chunk(slot1, w + 4 * 3, lane, srows);
  issue_chunk(gsrc, slot1, w + 4 * 5, lane);
  VMWAIT(7); proc_chunk(slot0, w + 4 * 4, lane, srows);
  issue_chunk(gsrc, slot0, w + 4 * 6, lane);
  VMWAIT(7); proc_chunk(slot1, w + 4 * 5, lane, srows);
  VMWAIT(0); proc_chunk(slot0, w + 4 * 6, lane, srows);

  __syncthreads();

  // --- conv+FC: 4 threads per image, i-ranges {0-6,7-13,14-20,21-24} ---
  const int sub = tid & 3;
  const int img = tid >> 2;               // 0..63
  const uint32_t* my = &srows[img * 29];
  int nd[10] = {0,0,0,0,0,0,0,0,0,0};
  int ilo = sub * 7;
  int ihi = ilo + 7; if (ihi > 25) ihi = 25;

  for (int i = ilo; i < ihi; ++i) {
    uint32_t r0 = my[i], r1 = my[i + 1], r2 = my[i + 2], r3 = my[i + 3];
#pragma unroll
    for (int c = 0; c < 3; ++c) {
      const uint32_t* W = wm[c];
      uint32_t s0, c0, s1, c1, s2, c2, s3, c3, s4, c4;
      FA( r0 ^ W[0],        (r0 ^ W[1])  >> 1, (r0 ^ W[2])  >> 2, s0, c0);
      FA((r0 ^ W[3]) >> 3,   r1 ^ W[4],        (r1 ^ W[5])  >> 1, s1, c1);
      FA((r1 ^ W[6]) >> 2,  (r1 ^ W[7])  >> 3,  r2 ^ W[8],        s2, c2);
      FA((r2 ^ W[9]) >> 1,  (r2 ^ W[10]) >> 2, (r2 ^ W[11]) >> 3, s3, c3);
      FA( r3 ^ W[12],       (r3 ^ W[13]) >> 1, (r3 ^ W[14]) >> 2, s4, c4);
      uint32_t t15 = (r3 ^ W[15]) >> 3;
      // weight-1 plane
      uint32_t u0, d0, u1, d1;
      FA(s0, s1, s2, u0, d0); FA(s3, s4, t15, u1, d1);
      uint32_t bb0 = u0 ^ u1, e0 = u0 & u1;
      // weight-2 plane
      uint32_t p0, q0, p1, q1, p2, q2;
      FA(c0, c1, c2, p0, q0); FA(c3, c4, d0, p1, q1); FA(d1, e0, p0, p2, q2);
      uint32_t bb1 = p1 ^ p2, q3 = p1 & p2;
      // weight-4 plane
      uint32_t r0_, r1_;
      FA(q0, q1, q2, r0_, r1_);
      uint32_t bb2 = r0_ ^ q3, r2_ = r0_ & q3;
      uint32_t bb3 = r1_ ^ r2_, bb4 = r1_ & r2_;
      // Nd>8, or Nd==8 with negative conv bias -> h sign bit
      uint32_t low = bb0 | bb1 | bb2;
      uint32_t neg = (bb4 | (bb3 & (low | sbc[c]))) & 0x1FFFFFFu;
      int ci = c * 25 + i;
      uint4 wA = *(const uint4*)&swf[ci * 12];
      uint4 wB = *(const uint4*)&swf[ci * 12 + 4];
      uint2 wC = *(const uint2*)&swf[ci * 12 + 8];
      nd[0] += __popc(neg ^ wA.x); nd[1] += __popc(neg ^ wA.y);
      nd[2] += __popc(neg ^ wA.z); nd[3] += __popc(neg ^ wA.w);
      nd[4] += __popc(neg ^ wB.x); nd[5] += __popc(neg ^ wB.y);
      nd[6] += __popc(neg ^ wB.z); nd[7] += __popc(neg ^ wB.w);
      nd[8] += __popc(neg ^ wC.x); nd[9] += __popc(neg ^ wC.y);
    }
  }

  // reduce partial mismatch counts across the 4 subs (lanes 4m..4m+3)
#pragma unroll
  for (int k = 0; k < 10; ++k) nd[k] += __shfl_xor(nd[k], 1);
#pragma unroll
  for (int k = 0; k < 10; ++k) nd[k] += __shfl_xor(nd[k], 2);

  if (sub == 0) {
    const size_t bi = (size_t)blockIdx.x * IMB + img;
    float* op = out + bi * 10;
#pragma unroll
    for (int k = 0; k < 10; k += 2) {
      float v0 = (float)(1875 - 2 * nd[k])     + b_fc[k];
      float v1 = (float)(1875 - 2 * nd[k + 1]) + b_fc[k + 1];
      float2 st;
      st.x = v0 < 0.f ? -1.f : (v0 > 0.f ? 1.f : 0.f);
      st.y = v1 < 0.f ? -1.f : (v1 > 0.f ? 1.f : 0.f);
      *(float2*)(op + k) = st;   // 8B aligned (bi*40)
    }
  }
}

extern "C" void kernel_launch(void* const* d_in, const int* in_sizes, int n_in,
                              void* d_out, int out_size, void* d_ws, size_t ws_size,
                              hipStream_t stream) {
  const float* x      = (const float*)d_in[0];
  const float* w_conv = (const float*)d_in[1];
  const float* b_conv = (const float*)d_in[2];
  const float* w_fc   = (const float*)d_in[3];
  const float* b_fc   = (const float*)d_in[4];
  bnn_fused<<<NBLK, 256, 0, stream>>>(x, w_conv, b_conv, w_fc, b_fc,
                                      (float*)d_out);
}

// Round 3
// 279.908 us; speedup vs baseline: 1.0839x; 1.0481x over previous
//
#include <hip/hip_runtime.h>
#include <stdint.h>

#define IMB 64              // images per block
#define NBLK (65536 / IMB)  // 1024 blocks
#define CHUNK_B 7168        // 64 rows * 112 B = 7 KB = 7 x 1KB wave-DMA ops
#define NCHUNK 28           // chunks per block (28 * 7168 = 64*784*4)

typedef float f32x2 __attribute__((ext_vector_type(2)));  // clang-native for NT store

// ---- async global->LDS DMA (16B/lane, 1KB/wave-instruction, no VGPR cost) ----
// aux=2 = NT (non-temporal) on gfx940+/gfx950 CPol: stream x through without
// allocating in L2/L3 -> our reads don't force writebacks of the poison fill's
// dirty L3 tail. x is read-once, so no reuse is forfeited.
__device__ __forceinline__ void gload16(const void* g, void* l) {
  __builtin_amdgcn_global_load_lds(
      (const __attribute__((address_space(1))) uint32_t*)g,
      (__attribute__((address_space(3))) uint32_t*)l, 16, 0, 2);
}

// counted vmcnt wait; memory clobber orders all memory ops, sched_barrier pins it
#define VMWAIT(N)                                                  \
  do {                                                             \
    asm volatile("s_waitcnt vmcnt(" #N ")" ::: "memory");          \
    __builtin_amdgcn_sched_barrier(0);                             \
  } while (0)

__device__ __forceinline__ void FA(uint32_t a, uint32_t b, uint32_t c,
                                   uint32_t& s, uint32_t& cy) {
  uint32_t ab = a ^ b;
  s = ab ^ c;
  cy = (a & b) | (ab & c);
}

// issue one 7KB chunk (7 x global_load_lds_dwordx4) into a wave-private slot
__device__ __forceinline__ void issue_chunk(const uint8_t* gsrc, uint8_t* slot,
                                            int c, int lane) {
  const uint8_t* s = gsrc + (size_t)c * CHUNK_B + lane * 16;
  uint8_t* d = slot + lane * 16;
#pragma unroll
  for (int i = 0; i < 7; ++i) gload16(s + i * 1024, d + i * 1024);
}

// one row per lane: 7 x ds_read_b128 -> 28 sign bits -> srows
__device__ __forceinline__ void proc_chunk(const uint8_t* slot, int c, int lane,
                                           uint32_t* srows) {
  const uint8_t* rp = slot + lane * 112;
  uint32_t m = 0;
#pragma unroll
  for (int q = 0; q < 7; ++q) {
    uint4 v = *(const uint4*)(rp + q * 16);
    uint32_t n = (v.x >> 31) | ((v.y >> 31) << 1) | ((v.z >> 31) << 2) |
                 ((v.w >> 31) << 3);
    m |= n << (4 * q);
  }
  uint32_t g = (uint32_t)c * 64u + (uint32_t)lane;  // block-local row id
  uint32_t img = g / 28u;
  uint32_t rowin = g - img * 28u;
  srows[img * 29 + rowin] = m;
}

// One fused kernel. Per block: 64 images.
//  stream: wave-private double-buffered NT global_load_lds DMA
//  pack:   per-lane row assembly from LDS raw floats
//  conv+FC: 4 threads/image, CSA bit-plane binary conv + XNOR-popcount, shfl reduce
__global__ __launch_bounds__(256, 2) void bnn_fused(
    const float* __restrict__ x, const float* __restrict__ w_conv,
    const float* __restrict__ b_conv, const float* __restrict__ w_fc,
    const float* __restrict__ b_fc, float* __restrict__ out)
{
  __shared__ __align__(16) uint8_t  raw[4 * 2 * CHUNK_B];  // 57344 B staging
  __shared__ uint32_t srows[IMB * 29];                     // stride 29: conflict-free
  __shared__ __align__(16) uint32_t swf[900];              // packed w_fc [75 ci][12]
  const int tid = threadIdx.x;
  const int w = tid >> 6, lane = tid & 63;

  // --- issue the first two DMA chunks immediately: their HBM latency overlaps
  //     the weight unpack below. Counted-wait invariant (robust to any compiler
  //     interleave of the unpack's vmem loads): VMWAIT(7) placed after issuing
  //     chunk c+1 retires everything issued before chunk c+1, including chunk c.
  const uint8_t* gsrc = (const uint8_t*)(x + (size_t)blockIdx.x * (IMB * 784));
  uint8_t* slot0 = &raw[(w * 2 + 0) * CHUNK_B];
  uint8_t* slot1 = &raw[(w * 2 + 1) * CHUNK_B];
  issue_chunk(gsrc, slot0, w + 4 * 0, lane);
  issue_chunk(gsrc, slot1, w + 4 * 1, lane);

  // conv weight sign masks (uniform addresses -> scalar loads / SGPRs)
  uint32_t wm[3][16], sbc[3];
#pragma unroll
  for (int c = 0; c < 3; ++c) {
#pragma unroll
    for (int uv = 0; uv < 16; ++uv)
      wm[c][uv] = (uint32_t)((int32_t)__float_as_uint(w_conv[c * 16 + uv]) >> 31);
    sbc[c] = (uint32_t)((int32_t)__float_as_uint(b_conv[c]) >> 31);
  }
  // fc bias (uniform -> scalar regs), hoisted out of the epilogue
  float bf[10];
#pragma unroll
  for (int k = 0; k < 10; ++k) bf[k] = b_fc[k];

  // unpack w_fc sign bits (redundant per block; 75 KB stays L2-resident);
  // these vector loads fly concurrently with the chunk-0/1 DMA above
  for (int s = tid; s < 750; s += 256) {
    int ci = s / 10, k = s - ci * 10;
    const float* wr = w_fc + k * 1875 + ci * 25;
    uint32_t m = 0;
#pragma unroll
    for (int j = 0; j < 25; ++j)
      m |= (__float_as_uint(wr[j]) >> 31) << j;
    swf[ci * 12 + k] = m;
  }

  // --- streaming phase: wave-private double-buffered DMA pipeline ---
  // wave w owns chunks {w, w+4, ..., w+24}; slot parity = chunk index & 1.
  VMWAIT(7); proc_chunk(slot0, w + 4 * 0, lane, srows);
  issue_chunk(gsrc, slot0, w + 4 * 2, lane);
  VMWAIT(7); proc_chunk(slot1, w + 4 * 1, lane, srows);
  issue_chunk(gsrc, slot1, w + 4 * 3, lane);
  VMWAIT(7); proc_chunk(slot0, w + 4 * 2, lane, srows);
  issue_chunk(gsrc, slot0, w + 4 * 4, lane);
  VMWAIT(7); proc_chunk(slot1, w + 4 * 3, lane, srows);
  issue_chunk(gsrc, slot1, w + 4 * 5, lane);
  VMWAIT(7); proc_chunk(slot0, w + 4 * 4, lane, srows);
  issue_chunk(gsrc, slot0, w + 4 * 6, lane);
  VMWAIT(7); proc_chunk(slot1, w + 4 * 5, lane, srows);
  VMWAIT(0); proc_chunk(slot0, w + 4 * 6, lane, srows);

  __syncthreads();

  // --- conv+FC: 4 threads per image, i-ranges {0-6,7-13,14-20,21-24} ---
  const int sub = tid & 3;
  const int img = tid >> 2;               // 0..63
  const uint32_t* my = &srows[img * 29];
  int nd[10] = {0,0,0,0,0,0,0,0,0,0};
  int ilo = sub * 7;
  int ihi = ilo + 7; if (ihi > 25) ihi = 25;

  for (int i = ilo; i < ihi; ++i) {
    uint32_t r0 = my[i], r1 = my[i + 1], r2 = my[i + 2], r3 = my[i + 3];
#pragma unroll
    for (int c = 0; c < 3; ++c) {
      const uint32_t* W = wm[c];
      uint32_t s0, c0, s1, c1, s2, c2, s3, c3, s4, c4;
      FA( r0 ^ W[0],        (r0 ^ W[1])  >> 1, (r0 ^ W[2])  >> 2, s0, c0);
      FA((r0 ^ W[3]) >> 3,   r1 ^ W[4],        (r1 ^ W[5])  >> 1, s1, c1);
      FA((r1 ^ W[6]) >> 2,  (r1 ^ W[7])  >> 3,  r2 ^ W[8],        s2, c2);
      FA((r2 ^ W[9]) >> 1,  (r2 ^ W[10]) >> 2, (r2 ^ W[11]) >> 3, s3, c3);
      FA( r3 ^ W[12],       (r3 ^ W[13]) >> 1, (r3 ^ W[14]) >> 2, s4, c4);
      uint32_t t15 = (r3 ^ W[15]) >> 3;
      // weight-1 plane
      uint32_t u0, d0, u1, d1;
      FA(s0, s1, s2, u0, d0); FA(s3, s4, t15, u1, d1);
      uint32_t bb0 = u0 ^ u1, e0 = u0 & u1;
      // weight-2 plane
      uint32_t p0, q0, p1, q1, p2, q2;
      FA(c0, c1, c2, p0, q0); FA(c3, c4, d0, p1, q1); FA(d1, e0, p0, p2, q2);
      uint32_t bb1 = p1 ^ p2, q3 = p1 & p2;
      // weight-4 plane
      uint32_t r0_, r1_;
      FA(q0, q1, q2, r0_, r1_);
      uint32_t bb2 = r0_ ^ q3, r2_ = r0_ & q3;
      uint32_t bb3 = r1_ ^ r2_, bb4 = r1_ & r2_;
      // Nd>8, or Nd==8 with negative conv bias -> h sign bit
      uint32_t low = bb0 | bb1 | bb2;
      uint32_t neg = (bb4 | (bb3 & (low | sbc[c]))) & 0x1FFFFFFu;
      int ci = c * 25 + i;
      uint4 wA = *(const uint4*)&swf[ci * 12];
      uint4 wB = *(const uint4*)&swf[ci * 12 + 4];
      uint2 wC = *(const uint2*)&swf[ci * 12 + 8];
      nd[0] += __popc(neg ^ wA.x); nd[1] += __popc(neg ^ wA.y);
      nd[2] += __popc(neg ^ wA.z); nd[3] += __popc(neg ^ wA.w);
      nd[4] += __popc(neg ^ wB.x); nd[5] += __popc(neg ^ wB.y);
      nd[6] += __popc(neg ^ wB.z); nd[7] += __popc(neg ^ wB.w);
      nd[8] += __popc(neg ^ wC.x); nd[9] += __popc(neg ^ wC.y);
    }
  }

  // reduce partial mismatch counts across the 4 subs (lanes 4m..4m+3)
#pragma unroll
  for (int k = 0; k < 10; ++k) nd[k] += __shfl_xor(nd[k], 1);
#pragma unroll
  for (int k = 0; k < 10; ++k) nd[k] += __shfl_xor(nd[k], 2);

  if (sub == 0) {
    const size_t bi = (size_t)blockIdx.x * IMB + img;
    float* op = out + bi * 10;
#pragma unroll
    for (int k = 0; k < 10; k += 2) {
      float v0 = (float)(1875 - 2 * nd[k])     + bf[k];
      float v1 = (float)(1875 - 2 * nd[k + 1]) + bf[k + 1];
      f32x2 st;
      st.x = v0 < 0.f ? -1.f : (v0 > 0.f ? 1.f : 0.f);
      st.y = v1 < 0.f ? -1.f : (v1 > 0.f ? 1.f : 0.f);
      __builtin_nontemporal_store(st, (f32x2*)(op + k));  // 8B aligned (bi*40)
    }
  }
}

extern "C" void kernel_launch(void* const* d_in, const int* in_sizes, int n_in,
                              void* d_out, int out_size, void* d_ws, size_t ws_size,
                              hipStream_t stream) {
  const float* x      = (const float*)d_in[0];
  const float* w_conv = (const float*)d_in[1];
  const float* b_conv = (const float*)d_in[2];
  const float* w_fc   = (const float*)d_in[3];
  const float* b_fc   = (const float*)d_in[4];
  bnn_fused<<<NBLK, 256, 0, stream>>>(x, w_conv, b_conv, w_fc, b_fc,
                                      (float*)d_out);
}

// Round 4
// 279.288 us; speedup vs baseline: 1.0863x; 1.0022x over previous
//
#include <hip/hip_runtime.h>
#include <stdint.h>

#define IMB 64              // images per block
#define NBLK (65536 / IMB)  // 1024 blocks
#define CHUNK_B 7168        // 64 rows * 112 B = 7 KB = 7 x 1KB wave-DMA ops
#define NCHUNK 28           // chunks per block; wave w owns chunks 7w..7w+6
                            // -> rows [448w,448w+448) -> images [16w,16w+16) (wave-private!)

typedef float f32x2 __attribute__((ext_vector_type(2)));  // clang-native for NT store

// ---- async global->LDS DMA (16B/lane, 1KB/wave-instruction, no VGPR cost) ----
// aux=2 = NT (non-temporal): stream x through without allocating in L2/L3 ->
// our reads don't force writebacks of the poison fill's dirty L3 tail.
__device__ __forceinline__ void gload16(const void* g, void* l) {
  __builtin_amdgcn_global_load_lds(
      (const __attribute__((address_space(1))) uint32_t*)g,
      (__attribute__((address_space(3))) uint32_t*)l, 16, 0, 2);
}

// counted vmcnt wait; memory clobber orders all memory ops, sched_barrier pins it
#define VMWAIT(N)                                                  \
  do {                                                             \
    asm volatile("s_waitcnt vmcnt(" #N ")" ::: "memory");          \
    __builtin_amdgcn_sched_barrier(0);                             \
  } while (0)

#define LGKMWAIT0()                                                \
  do {                                                             \
    asm volatile("s_waitcnt lgkmcnt(0)" ::: "memory");             \
    __builtin_amdgcn_sched_barrier(0);                             \
  } while (0)

__device__ __forceinline__ void FA(uint32_t a, uint32_t b, uint32_t c,
                                   uint32_t& s, uint32_t& cy) {
  uint32_t ab = a ^ b;
  s = ab ^ c;
  cy = (a & b) | (ab & c);
}

// issue one 7KB chunk (7 x global_load_lds_dwordx4) into a wave-private slot
__device__ __forceinline__ void issue_chunk(const uint8_t* gsrc, uint8_t* slot,
                                            int c, int lane) {
  const uint8_t* s = gsrc + (size_t)c * CHUNK_B + lane * 16;
  uint8_t* d = slot + lane * 16;
#pragma unroll
  for (int i = 0; i < 7; ++i) gload16(s + i * 1024, d + i * 1024);
}

// one row per lane: 7 x ds_read_b128 -> 28 sign bits -> srows (wave-private range)
__device__ __forceinline__ void proc_chunk(const uint8_t* slot, int c, int lane,
                                           uint32_t* srows) {
  const uint8_t* rp = slot + lane * 112;
  uint32_t m = 0;
#pragma unroll
  for (int q = 0; q < 7; ++q) {
    uint4 v = *(const uint4*)(rp + q * 16);
    uint32_t n = (v.x >> 31) | ((v.y >> 31) << 1) | ((v.z >> 31) << 2) |
                 ((v.w >> 31) << 3);
    m |= n << (4 * q);
  }
  uint32_t g = (uint32_t)c * 64u + (uint32_t)lane;  // block-local row id
  uint32_t img = g / 28u;
  uint32_t rowin = g - img * 28u;
  srows[img * 29 + rowin] = m;
}

// One fused kernel. Per block: 64 images, 4 waves, 16 images/wave (wave-private).
//  stream: wave-private double-buffered NT global_load_lds DMA
//  conv+FC: 4 threads/image, CSA bit-plane binary conv + XNOR-popcount, shfl reduce
//  NO block-wide barrier between stream and compute: srows is wave-private;
//  only swf needs one raw s_barrier (lgkmcnt-only -> DMA stays in flight).
__global__ __launch_bounds__(256, 2) void bnn_fused(
    const float* __restrict__ x, const float* __restrict__ w_conv,
    const float* __restrict__ b_conv, const float* __restrict__ w_fc,
    const float* __restrict__ b_fc, float* __restrict__ out)
{
  __shared__ __align__(16) uint8_t  raw[4 * 2 * CHUNK_B];  // 57344 B staging
  __shared__ uint32_t srows[IMB * 29];                     // stride 29: conflict-free
  __shared__ __align__(16) uint32_t swf[900];              // packed w_fc [75 ci][12]
  const int tid = threadIdx.x;
  const int w = tid >> 6, lane = tid & 63;

  // --- issue the first two DMA chunks immediately: their HBM latency overlaps
  //     the weight unpack below. Counted-wait invariant (in-order vmcnt retire):
  //     VMWAIT(7) after issuing chunk c+1 retires everything issued before
  //     chunk c+1, including chunk c and all unpack loads.
  const uint8_t* gsrc = (const uint8_t*)(x + (size_t)blockIdx.x * (IMB * 784));
  uint8_t* slot0 = &raw[(w * 2 + 0) * CHUNK_B];
  uint8_t* slot1 = &raw[(w * 2 + 1) * CHUNK_B];
  const int c0 = 7 * w;  // wave-contiguous chunk base
  issue_chunk(gsrc, slot0, c0 + 0, lane);
  issue_chunk(gsrc, slot1, c0 + 1, lane);

  // conv weight sign masks (uniform addresses -> scalar loads / SGPRs)
  uint32_t wm[3][16], sbc[3];
#pragma unroll
  for (int c = 0; c < 3; ++c) {
#pragma unroll
    for (int uv = 0; uv < 16; ++uv)
      wm[c][uv] = (uint32_t)((int32_t)__float_as_uint(w_conv[c * 16 + uv]) >> 31);
    sbc[c] = (uint32_t)((int32_t)__float_as_uint(b_conv[c]) >> 31);
  }
  // fc bias (uniform -> scalar regs), hoisted out of the epilogue
  float bf[10];
#pragma unroll
  for (int k = 0; k < 10; ++k) bf[k] = b_fc[k];

  // unpack w_fc sign bits (redundant per block; 75 KB stays L2-resident);
  // these vector loads fly concurrently with the chunk-0/1 DMA above
  for (int s = tid; s < 750; s += 256) {
    int ci = s / 10, k = s - ci * 10;
    const float* wr = w_fc + k * 1875 + ci * 25;
    uint32_t m = 0;
#pragma unroll
    for (int j = 0; j < 25; ++j)
      m |= (__float_as_uint(wr[j]) >> 31) << j;
    swf[ci * 12 + k] = m;
  }

  // swf coherence: drain LDS writes, then RAW s_barrier (does NOT drain vmcnt,
  // so the chunk-0/1 DMA stays in flight across it -- __syncthreads would kill it)
  LGKMWAIT0();
  __builtin_amdgcn_s_barrier();

  // --- streaming phase: wave-private double-buffered DMA pipeline ---
  VMWAIT(7); proc_chunk(slot0, c0 + 0, lane, srows);
  issue_chunk(gsrc, slot0, c0 + 2, lane);
  VMWAIT(7); proc_chunk(slot1, c0 + 1, lane, srows);
  issue_chunk(gsrc, slot1, c0 + 3, lane);
  VMWAIT(7); proc_chunk(slot0, c0 + 2, lane, srows);
  issue_chunk(gsrc, slot0, c0 + 4, lane);
  VMWAIT(7); proc_chunk(slot1, c0 + 3, lane, srows);
  issue_chunk(gsrc, slot1, c0 + 5, lane);
  VMWAIT(7); proc_chunk(slot0, c0 + 4, lane, srows);
  issue_chunk(gsrc, slot0, c0 + 6, lane);
  VMWAIT(7); proc_chunk(slot1, c0 + 5, lane, srows);
  VMWAIT(0); proc_chunk(slot0, c0 + 6, lane, srows);

  // cross-lane LDS visibility within the (lockstep) wave: drain ds_writes.
  // No block barrier: srows rows for this wave's images were written only by
  // this wave (contiguous chunk ownership).
  LGKMWAIT0();

  // --- conv+FC: 4 threads per image, i-ranges {0-6,7-13,14-20,21-24} ---
  const int sub = tid & 3;
  const int img = tid >> 2;               // wave w -> imgs [16w,16w+16): wave-private
  const uint32_t* my = &srows[img * 29];
  int nd[10] = {0,0,0,0,0,0,0,0,0,0};
  int ilo = sub * 7;
  int ihi = ilo + 7; if (ihi > 25) ihi = 25;

  for (int i = ilo; i < ihi; ++i) {
    uint32_t r0 = my[i], r1 = my[i + 1], r2 = my[i + 2], r3 = my[i + 3];
#pragma unroll
    for (int c = 0; c < 3; ++c) {
      const uint32_t* W = wm[c];
      uint32_t s0, c0_, s1, c1, s2, c2, s3, c3, s4, c4;
      FA( r0 ^ W[0],        (r0 ^ W[1])  >> 1, (r0 ^ W[2])  >> 2, s0, c0_);
      FA((r0 ^ W[3]) >> 3,   r1 ^ W[4],        (r1 ^ W[5])  >> 1, s1, c1);
      FA((r1 ^ W[6]) >> 2,  (r1 ^ W[7])  >> 3,  r2 ^ W[8],        s2, c2);
      FA((r2 ^ W[9]) >> 1,  (r2 ^ W[10]) >> 2, (r2 ^ W[11]) >> 3, s3, c3);
      FA( r3 ^ W[12],       (r3 ^ W[13]) >> 1, (r3 ^ W[14]) >> 2, s4, c4);
      uint32_t t15 = (r3 ^ W[15]) >> 3;
      // weight-1 plane
      uint32_t u0, d0, u1, d1;
      FA(s0, s1, s2, u0, d0); FA(s3, s4, t15, u1, d1);
      uint32_t bb0 = u0 ^ u1, e0 = u0 & u1;
      // weight-2 plane
      uint32_t p0, q0, p1, q1, p2, q2;
      FA(c0_, c1, c2, p0, q0); FA(c3, c4, d0, p1, q1); FA(d1, e0, p0, p2, q2);
      uint32_t bb1 = p1 ^ p2, q3 = p1 & p2;
      // weight-4 plane
      uint32_t r0_, r1_;
      FA(q0, q1, q2, r0_, r1_);
      uint32_t bb2 = r0_ ^ q3, r2_ = r0_ & q3;
      uint32_t bb3 = r1_ ^ r2_, bb4 = r1_ & r2_;
      // Nd>8, or Nd==8 with negative conv bias -> h sign bit
      uint32_t low = bb0 | bb1 | bb2;
      uint32_t neg = (bb4 | (bb3 & (low | sbc[c]))) & 0x1FFFFFFu;
      int ci = c * 25 + i;
      uint4 wA = *(const uint4*)&swf[ci * 12];
      uint4 wB = *(const uint4*)&swf[ci * 12 + 4];
      uint2 wC = *(const uint2*)&swf[ci * 12 + 8];
      nd[0] += __popc(neg ^ wA.x); nd[1] += __popc(neg ^ wA.y);
      nd[2] += __popc(neg ^ wA.z); nd[3] += __popc(neg ^ wA.w);
      nd[4] += __popc(neg ^ wB.x); nd[5] += __popc(neg ^ wB.y);
      nd[6] += __popc(neg ^ wB.z); nd[7] += __popc(neg ^ wB.w);
      nd[8] += __popc(neg ^ wC.x); nd[9] += __popc(neg ^ wC.y);
    }
  }

  // reduce partial mismatch counts across the 4 subs (lanes 4m..4m+3)
#pragma unroll
  for (int k = 0; k < 10; ++k) nd[k] += __shfl_xor(nd[k], 1);
#pragma unroll
  for (int k = 0; k < 10; ++k) nd[k] += __shfl_xor(nd[k], 2);

  if (sub == 0) {
    const size_t bi = (size_t)blockIdx.x * IMB + img;
    float* op = out + bi * 10;
#pragma unroll
    for (int k = 0; k < 10; k += 2) {
      float v0 = (float)(1875 - 2 * nd[k])     + bf[k];
      float v1 = (float)(1875 - 2 * nd[k + 1]) + bf[k + 1];
      f32x2 st;
      st.x = v0 < 0.f ? -1.f : (v0 > 0.f ? 1.f : 0.f);
      st.y = v1 < 0.f ? -1.f : (v1 > 0.f ? 1.f : 0.f);
      __builtin_nontemporal_store(st, (f32x2*)(op + k));  // 8B aligned (bi*40)
    }
  }
}

extern "C" void kernel_launch(void* const* d_in, const int* in_sizes, int n_in,
                              void* d_out, int out_size, void* d_ws, size_t ws_size,
                              hipStream_t stream) {
  const float* x      = (const float*)d_in[0];
  const float* w_conv = (const float*)d_in[1];
  const float* b_conv = (const float*)d_in[2];
  const float* w_fc   = (const float*)d_in[3];
  const float* b_fc   = (const float*)d_in[4];
  bnn_fused<<<NBLK, 256, 0, stream>>>(x, w_conv, b_conv, w_fc, b_fc,
                                      (float*)d_out);
}